// Round 7
// baseline (178.607 us; speedup 1.0000x reference)
//
#include <hip/hip_runtime.h>
#include <hip/hip_bf16.h>
#include <stdint.h>

#define B_ 8
#define C_ 512
#define N_ 2048

typedef __bf16 bf16_t;
typedef bf16_t bf16x8 __attribute__((ext_vector_type(8)));
typedef bf16_t bf16x4 __attribute__((ext_vector_type(4)));
typedef float f32x4 __attribute__((ext_vector_type(4)));

// ---------------------------------------------------------------------------
// Cast two 512x512 weight matrices to bf16 (Wk, Wv -> contiguous).
// ---------------------------------------------------------------------------
__global__ __launch_bounds__(256) void cast_w_kernel(
    const float* __restrict__ w0, const float* __restrict__ w1,
    bf16_t* __restrict__ out)
{
    const float* src = (blockIdx.z == 0) ? w0 : w1;
    bf16_t* dst = out + (size_t)blockIdx.z * (C_ * C_);
    int i = (blockIdx.x * 256 + threadIdx.x) * 4;
    float4 f = *(const float4*)(src + i);
    bf16x4 o;
    o[0] = (bf16_t)f.x; o[1] = (bf16_t)f.y; o[2] = (bf16_t)f.z; o[3] = (bf16_t)f.w;
    *(bf16x4*)(dst + i) = o;
}

// ---------------------------------------------------------------------------
// Transpose-cast Wq: fp32 [C][C] -> bf16 out[i][c] = in[c][i]. grid (8,8).
// ---------------------------------------------------------------------------
__global__ __launch_bounds__(256) void transpose_cast_w_kernel(
    const float* __restrict__ in, bf16_t* __restrict__ out)
{
    __shared__ bf16_t tile[64][65];
    const int i0 = blockIdx.x * 64;
    const int c0 = blockIdx.y * 64;
    const int t = threadIdx.x;
    const int cx = (t & 15) * 4;
    const int ry = t >> 4;
#pragma unroll
    for (int r = ry; r < 64; r += 16) {
        float4 f = *(const float4*)&in[(size_t)(c0 + r) * C_ + i0 + cx];
        tile[r][cx + 0] = (bf16_t)f.x;
        tile[r][cx + 1] = (bf16_t)f.y;
        tile[r][cx + 2] = (bf16_t)f.z;
        tile[r][cx + 3] = (bf16_t)f.w;
    }
    __syncthreads();
    const int c4 = (t & 15) * 4;
    const int rb = t >> 4;
#pragma unroll
    for (int r = rb; r < 64; r += 16) {
        bf16x4 o;
        o[0] = tile[c4 + 0][r];
        o[1] = tile[c4 + 1][r];
        o[2] = tile[c4 + 2][r];
        o[3] = tile[c4 + 3][r];
        *(bf16x4*)&out[(size_t)(i0 + r) * C_ + c0 + c4] = o;
    }
}

// ---------------------------------------------------------------------------
// Transpose-cast: fp32 [B][C][N] -> bf16 [B][N][C]. grid (N/64, C/64, B).
// (r1-proven kernel; used for q only.)
// ---------------------------------------------------------------------------
__global__ __launch_bounds__(256) void transpose_cast_kernel(
    const float* __restrict__ in, bf16_t* __restrict__ out)
{
    __shared__ bf16_t tile[64][65];
    const int b = blockIdx.z;
    const float* src = in + (size_t)b * C_ * N_;
    bf16_t* dst = out + (size_t)b * N_ * C_;
    const int n0 = blockIdx.x * 64;
    const int c0 = blockIdx.y * 64;
    const int t = threadIdx.x;
    const int cx = (t & 15) * 4;
    const int ry = t >> 4;
#pragma unroll
    for (int r = ry; r < 64; r += 16) {
        float4 f = *(const float4*)&src[(size_t)(c0 + r) * N_ + n0 + cx];
        tile[r][cx + 0] = (bf16_t)f.x;
        tile[r][cx + 1] = (bf16_t)f.y;
        tile[r][cx + 2] = (bf16_t)f.z;
        tile[r][cx + 3] = (bf16_t)f.w;
    }
    __syncthreads();
    const int c4 = (t & 15) * 4;
    const int rb = t >> 4;
#pragma unroll
    for (int r = rb; r < 64; r += 16) {
        bf16x4 o;
        o[0] = tile[c4 + 0][r];
        o[1] = tile[c4 + 1][r];
        o[2] = tile[c4 + 2][r];
        o[3] = tile[c4 + 3][r];
        *(bf16x4*)&dst[(size_t)(n0 + r) * C_ + c0 + c4] = o;
    }
}

// ---------------------------------------------------------------------------
// D GEMM: Dp[z][i,j] = sum_{n in split} k[b][i,n] * v[b][j,n]  (NT, fp32 in,
// cast to bf16 in registers -> swizzled ds_write_b128; both operands are
// K-contiguous rows -> NO transpose staging). split-K 4, z = b*4+sp.
// Side products (fp32, from pre-cast registers): sk[b][i]=sum_n k, sv[b][j]=
// sum_n v, accumulated by n0==0 / m0==0 blocks via atomicAdd (buffer
// pre-zeroed by hipMemsetAsync).
// Single-buffer 2-barrier loop + register prefetch of tile t+1 (r6-proven,
// race-free). Tile 128x128, BK=64, 4 waves 2x2.
// ---------------------------------------------------------------------------
__global__ __launch_bounds__(256) void gemm_d(
    const float* __restrict__ Kin, const float* __restrict__ Vin,
    bf16_t* __restrict__ Dp, float* __restrict__ sk, float* __restrict__ sv)
{
    __shared__ __align__(16) bf16_t As[128 * 64];
    __shared__ __align__(16) bf16_t Bs[128 * 64];

    const int tid = threadIdx.x, lane = tid & 63, wave = tid >> 6;
    const int wr = wave >> 1, wc = wave & 1;
    const int bz = blockIdx.z >> 2, sp = blockIdx.z & 3;
    const int m0 = blockIdx.y * 128, n0 = blockIdx.x * 128;
    const float* A  = Kin + (size_t)bz * C_ * N_;
    const float* Bv = Vin + (size_t)bz * C_ * N_;
    const int kbeg = sp * 512;

    const int srow = tid >> 1;        // 0..127
    const int sc0  = (tid & 1) * 32;  // float col offset within BK=64

    f32x4 acc[4][4];
#pragma unroll
    for (int i = 0; i < 4; ++i)
#pragma unroll
        for (int j = 0; j < 4; ++j) acc[i][j] = 0.f;

    float4 xa[8], xb[8];
    float sumA = 0.f, sumB = 0.f;

    auto load_t = [&](int t) {
        const float* ga = A  + (size_t)(m0 + srow) * N_ + kbeg + t * 64 + sc0;
        const float* gb = Bv + (size_t)(n0 + srow) * N_ + kbeg + t * 64 + sc0;
#pragma unroll
        for (int p = 0; p < 8; ++p) {
            xa[p] = *(const float4*)(ga + 4 * p);
            xb[p] = *(const float4*)(gb + 4 * p);
        }
    };
    auto write_t = [&]() {
        if (blockIdx.x == 0) {
#pragma unroll
            for (int p = 0; p < 8; ++p) sumA += xa[p].x + xa[p].y + xa[p].z + xa[p].w;
        }
        if (blockIdx.y == 0) {
#pragma unroll
            for (int p = 0; p < 8; ++p) sumB += xb[p].x + xb[p].y + xb[p].z + xb[p].w;
        }
#pragma unroll
        for (int h = 0; h < 4; ++h) {
            bf16x8 pa, pb;
#pragma unroll
            for (int j = 0; j < 4; ++j) {
                pa[j]     = (bf16_t)((&xa[2 * h].x)[j]);
                pa[j + 4] = (bf16_t)((&xa[2 * h + 1].x)[j]);
                pb[j]     = (bf16_t)((&xb[2 * h].x)[j]);
                pb[j + 4] = (bf16_t)((&xb[2 * h + 1].x)[j]);
            }
            const int c = (sc0 >> 3) + h;                  // source chunk 0..7
            const int off = srow * 128 + ((c ^ (srow & 7)) << 4);
            *(bf16x8*)((char*)As + off) = pa;
            *(bf16x8*)((char*)Bs + off) = pb;
        }
    };
    auto compute = [&]() {
#pragma unroll
        for (int kk = 0; kk < 64; kk += 32) {
            bf16x8 af[4], bfr[4];
            const int kcol = kk + (lane >> 4) * 8;
            const int kc = kcol >> 3;
#pragma unroll
            for (int m = 0; m < 4; ++m) {
                const int row = wr * 64 + (lane & 15) + m * 16;
                af[m] = *(const bf16x8*)((const char*)As + row * 128 +
                                         ((kc ^ (row & 7)) << 4));
            }
#pragma unroll
            for (int n = 0; n < 4; ++n) {
                const int row = wc * 64 + (lane & 15) + n * 16;
                bfr[n] = *(const bf16x8*)((const char*)Bs + row * 128 +
                                          ((kc ^ (row & 7)) << 4));
            }
#pragma unroll
            for (int m = 0; m < 4; ++m)
#pragma unroll
                for (int n = 0; n < 4; ++n)
                    acc[m][n] = __builtin_amdgcn_mfma_f32_16x16x32_bf16(
                        af[m], bfr[n], acc[m][n], 0, 0, 0);
        }
    };

    load_t(0);
    for (int t = 0; t < 8; ++t) {
        write_t();                       // regs(tile t) -> LDS
        __syncthreads();                 // barrier-1
        if (t < 7) load_t(t + 1);        // prefetch hidden by compute
        compute();
        __syncthreads();                 // barrier-2
    }

    // C-write (bf16 partial) + side sums
    const int rj = (lane >> 4) * 4;
    const int cc = lane & 15;
    const size_t sCC = (size_t)C_ * C_;
#pragma unroll
    for (int m = 0; m < 4; ++m) {
#pragma unroll
        for (int n = 0; n < 4; ++n) {
            const int col = n0 + wc * 64 + n * 16 + cc;
            f32x4 vv = acc[m][n];
#pragma unroll
            for (int j = 0; j < 4; ++j) {
                const int row = m0 + wr * 64 + m * 16 + rj + j;
                Dp[(size_t)blockIdx.z * sCC + (size_t)row * C_ + col] = (bf16_t)vv[j];
            }
        }
    }
    if (blockIdx.x == 0) {
        float o = sumA + __shfl_xor(sumA, 1, 64);
        if (!(tid & 1)) atomicAdd(&sk[bz * C_ + m0 + srow], o);
    }
    if (blockIdx.y == 0) {
        float o = sumB + __shfl_xor(sumB, 1, 64);
        if (!(tid & 1)) atomicAdd(&sv[bz * C_ + n0 + srow], o);
    }
}

// ---------------------------------------------------------------------------
// Sum 4 split-K bf16 partials -> bf16. Pt: [B_][4][C_*C_], Out: [B_][C_*C_].
// ---------------------------------------------------------------------------
__global__ __launch_bounds__(256) void reduce_splitk_kernel(
    const bf16_t* __restrict__ Pt, bf16_t* __restrict__ Out)
{
    const size_t sCC = (size_t)C_ * C_;
    size_t idx = ((size_t)blockIdx.x * 256 + threadIdx.x) * 8;
    size_t b = idx / sCC;
    size_t r = idx - b * sCC;
    const bf16_t* base = Pt + (b * 4) * sCC + r;
    float acc[8];
#pragma unroll
    for (int j = 0; j < 8; ++j) acc[j] = 0.f;
#pragma unroll
    for (int s = 0; s < 4; ++s) {
        bf16x8 pv = *(const bf16x8*)(base + (size_t)s * sCC);
#pragma unroll
        for (int j = 0; j < 8; ++j) acc[j] += (float)pv[j];
    }
    bf16x8 o;
#pragma unroll
    for (int j = 0; j < 8; ++j) o[j] = (bf16_t)acc[j];
    *(bf16x8*)(Out + idx) = o;
}

// ---------------------------------------------------------------------------
// u[b] = Wvb . sv[b],  w[b] = Wkb . sk[b]   (per batch, 512-dots).
// grid (2*B_): block b2 -> sel=b2&1 (0:u, 1:w), b=b2>>1. 2 rows/thread.
// ---------------------------------------------------------------------------
__global__ __launch_bounds__(256) void matvec_uw_kernel(
    const bf16_t* __restrict__ Wvb, const bf16_t* __restrict__ Wkb,
    const float* __restrict__ sv, const float* __restrict__ sk,
    float* __restrict__ u, float* __restrict__ w)
{
    const int b2 = blockIdx.x;
    const int b = b2 >> 1, sel = b2 & 1;
    const bf16_t* W = sel ? Wkb : Wvb;
    const float* s  = (sel ? sk : sv) + (size_t)b * C_;
    float* o        = (sel ? w : u) + (size_t)b * C_;
    const int c = threadIdx.x * 2;
#pragma unroll
    for (int rr = 0; rr < 2; ++rr) {
        const bf16_t* row = W + (size_t)(c + rr) * C_;
        float acc = 0.f;
        for (int j = 0; j < C_; j += 8) {
            bf16x8 vv = *(const bf16x8*)(row + j);
#pragma unroll
            for (int t = 0; t < 8; ++t) acc += (float)vv[t] * s[j + t];
        }
        o[c + rr] = acc;
    }
}

// ---------------------------------------------------------------------------
// Lean bf16 NT GEMM (no split): C[m,n] = sum_k A[m,k]*B[n,k].
// global_load_lds both sides with source-chunk pre-swizzle + swizzled reads
// (r6-proven). blockIdx.z = batch; sA/sB/sC may be 0 for shared operands.
// EPI 0: bf16 out.
// EPI 1: bf16 out + rank-1:  val += e0[bz*C+row]*e1[col]
//                                 + e2[row]*(e3[bz*C+col] + 2048*e1[col])
// EPI 2: fp32 out + e0[bz*C+row] + resid[bz*sC + row*Nn + col]
// ---------------------------------------------------------------------------
template <int EPI>
__global__ __launch_bounds__(256) void gemm_nt2(
    const bf16_t* __restrict__ A, const bf16_t* __restrict__ Bm,
    void* __restrict__ Cout, int Nn, int K, size_t sA, size_t sB, size_t sC,
    const float* __restrict__ e0, const float* __restrict__ e1,
    const float* __restrict__ e2, const float* __restrict__ e3,
    const float* __restrict__ resid)
{
    __shared__ __align__(16) bf16_t As[128 * 64];
    __shared__ __align__(16) bf16_t Bs[128 * 64];

    const int tid = threadIdx.x, lane = tid & 63, wave = tid >> 6;
    const int wr = wave >> 1, wc = wave & 1;
    const int bz = blockIdx.z;
    const bf16_t* Ab = A + (size_t)bz * sA;
    const bf16_t* Bb = Bm + (size_t)bz * sB;
    const int m0 = blockIdx.y * 128, n0 = blockIdx.x * 128;

    f32x4 acc[4][4];
#pragma unroll
    for (int i = 0; i < 4; ++i)
#pragma unroll
        for (int j = 0; j < 4; ++j) acc[i][j] = 0.f;

    const int srow = tid >> 3;
    const int scol = ((tid & 7) ^ (srow & 7)) * 8;
    const int ldso = tid * 16;
    const int nt = K / 64;

    for (int t = 0; t < nt; ++t) {
        const bf16_t* ga = Ab + (size_t)(m0 + srow) * K + t * 64 + scol;
        const bf16_t* gb = Bb + (size_t)(n0 + srow) * K + t * 64 + scol;
#pragma unroll
        for (int p = 0; p < 4; ++p)
            __builtin_amdgcn_global_load_lds(
                (const __attribute__((address_space(1))) void*)(ga + (size_t)p * 32 * K),
                (__attribute__((address_space(3))) void*)((char*)As + ldso + p * 4096),
                16, 0, 0);
#pragma unroll
        for (int p = 0; p < 4; ++p)
            __builtin_amdgcn_global_load_lds(
                (const __attribute__((address_space(1))) void*)(gb + (size_t)p * 32 * K),
                (__attribute__((address_space(3))) void*)((char*)Bs + ldso + p * 4096),
                16, 0, 0);
        __syncthreads();

#pragma unroll
        for (int kk = 0; kk < 64; kk += 32) {
            bf16x8 af[4], bfr[4];
            const int kcol = kk + (lane >> 4) * 8;
            const int kc = kcol >> 3;
#pragma unroll
            for (int m = 0; m < 4; ++m) {
                const int row = wr * 64 + (lane & 15) + m * 16;
                af[m] = *(const bf16x8*)((const char*)As + row * 128 +
                                         ((kc ^ (row & 7)) << 4));
            }
#pragma unroll
            for (int n = 0; n < 4; ++n) {
                const int row = wc * 64 + (lane & 15) + n * 16;
                bfr[n] = *(const bf16x8*)((const char*)Bs + row * 128 +
                                          ((kc ^ (row & 7)) << 4));
            }
#pragma unroll
            for (int m = 0; m < 4; ++m)
#pragma unroll
                for (int n = 0; n < 4; ++n)
                    acc[m][n] = __builtin_amdgcn_mfma_f32_16x16x32_bf16(
                        af[m], bfr[n], acc[m][n], 0, 0, 0);
        }
        __syncthreads();
    }

    const int rj = (lane >> 4) * 4;
    const int cc = lane & 15;
#pragma unroll
    for (int m = 0; m < 4; ++m) {
#pragma unroll
        for (int n = 0; n < 4; ++n) {
            const int col = n0 + wc * 64 + n * 16 + cc;
            f32x4 vv = acc[m][n];
#pragma unroll
            for (int j = 0; j < 4; ++j) {
                const int row = m0 + wr * 64 + m * 16 + rj + j;
                float val = vv[j];
                if (EPI == 1)
                    val += e0[bz * C_ + row] * e1[col] +
                           e2[row] * (e3[bz * C_ + col] + 2048.0f * e1[col]);
                if (EPI == 2) {
                    float* op = (float*)Cout + (size_t)bz * sC + (size_t)row * Nn + col;
                    *op = val + e0[bz * C_ + row] +
                          resid[(size_t)bz * sC + (size_t)row * Nn + col];
                } else {
                    ((bf16_t*)Cout)[(size_t)bz * sC + (size_t)row * Nn + col] = (bf16_t)val;
                }
            }
        }
    }
}

// ---------------------------------------------------------------------------
// h[b][c] = sum_c1 St[b][c,c1] * bq[c1].
// ---------------------------------------------------------------------------
__global__ __launch_bounds__(256) void compute_h_kernel(
    const bf16_t* __restrict__ St, const float* __restrict__ bq,
    float* __restrict__ h)
{
    const int b = blockIdx.x;
    const int c = threadIdx.x * 2;
#pragma unroll
    for (int rr = 0; rr < 2; ++rr) {
        const bf16_t* row = St + ((size_t)b * C_ + c + rr) * C_;
        float acc = 0.f;
        for (int j = 0; j < C_; j += 8) {
            bf16x8 vv = *(const bf16x8*)(row + j);
#pragma unroll
            for (int t = 0; t < 8; ++t) acc += (float)vv[t] * bq[j + t];
        }
        h[b * C_ + c + rr] = acc;
    }
}

// ---------------------------------------------------------------------------
extern "C" void kernel_launch(void* const* d_in, const int* in_sizes, int n_in,
                              void* d_out, int out_size, void* d_ws, size_t ws_size,
                              hipStream_t stream)
{
    (void)in_sizes; (void)n_in; (void)out_size; (void)ws_size;
    const float* q  = (const float*)d_in[0];
    const float* k  = (const float*)d_in[1];
    const float* v  = (const float*)d_in[2];
    const float* wq = (const float*)d_in[3];
    const float* bq = (const float*)d_in[4];
    const float* wk = (const float*)d_in[5];
    const float* bk = (const float*)d_in[6];
    const float* wv = (const float*)d_in[7];
    const float* bv = (const float*)d_in[8];
    float* out = (float*)d_out;

    char* ws = (char*)d_ws;
    const size_t WSZ = (size_t)C_ * C_ * 2;            // 512 KB
    const size_t TSZ = (size_t)B_ * N_ * C_ * 2;       // 16.78 MB
    const size_t SCZ = (size_t)B_ * C_ * C_ * 2;       // 4.19 MB
    const size_t VSZ = (size_t)B_ * C_ * 4;            // 16 KB (per-batch fp32 vec)
    size_t off = 0;
    bf16_t* Wkb  = (bf16_t*)(ws + off); off += WSZ;
    bf16_t* Wvb  = (bf16_t*)(ws + off); off += WSZ;
    bf16_t* WqTb = (bf16_t*)(ws + off); off += WSZ;
    bf16_t* qT   = (bf16_t*)(ws + off); off += TSZ;
    bf16_t* Dp   = (bf16_t*)(ws + off); off += TSZ;    // split-K partials of D
    bf16_t* D    = (bf16_t*)(ws + off); off += SCZ;
    bf16_t* P1   = (bf16_t*)(ws + off); off += SCZ;
    bf16_t* St   = (bf16_t*)(ws + off); off += SCZ;
    bf16_t* HT   = (bf16_t*)(ws + off); off += SCZ;
    float*  skv  = (float*)(ws + off);  off += 2 * VSZ; // sk | sv (zeroed)
    float*  uu   = (float*)(ws + off);  off += VSZ;
    float*  wwv  = (float*)(ws + off);  off += VSZ;
    float*  hb   = (float*)(ws + off);  off += VSZ;
    float*  sk   = skv;
    float*  sv   = skv + (size_t)B_ * C_;

    const dim3 blk(256);
    const size_t sBN = (size_t)N_ * C_;
    const size_t sCC = (size_t)C_ * C_;

    // 0. zero the atomic-sum buffers (graph-capture-safe)
    hipMemsetAsync(skv, 0, 2 * VSZ, stream);

    // 1. weights: Wk,Wv -> bf16; WqT = Wq^T bf16; qT = q^T bf16 [B,N,C]
    cast_w_kernel<<<dim3(256, 1, 2), blk, 0, stream>>>(wk, wv, Wkb);
    transpose_cast_w_kernel<<<dim3(C_ / 64, C_ / 64), blk, 0, stream>>>(wq, WqTb);
    transpose_cast_kernel<<<dim3(N_ / 64, C_ / 64, B_), blk, 0, stream>>>(q, qT);

    // 2. Dp[z] = partial_n k.v^T (split-K 4) + sk/sv side sums; reduce -> D
    gemm_d<<<dim3(C_ / 128, C_ / 128, B_ * 4), blk, 0, stream>>>(k, v, Dp, sk, sv);
    reduce_splitk_kernel<<<dim3((B_ * sCC) / (256 * 8)), blk, 0, stream>>>(Dp, D);

    // 3. u = Wv.sv, w = Wk.sk
    matvec_uw_kernel<<<dim3(2 * B_), blk, 0, stream>>>(Wvb, Wkb, sv, sk, uu, wwv);

    // 4. P1[c2,i] = sum_j Wv[c2,j] D[i,j]
    gemm_nt2<0><<<dim3(C_ / 128, C_ / 128, B_), blk, 0, stream>>>(
        Wvb, D, (void*)P1, C_, C_, 0, sCC, sCC, nullptr, nullptr, nullptr, nullptr, nullptr);

    // 5. St[c2,c1] = sum_i P1[c2,i] Wk[c1,i] + u[c2]bk[c1] + bv[c2]w[c1] + N bv bk
    gemm_nt2<1><<<dim3(C_ / 128, C_ / 128, B_), blk, 0, stream>>>(
        P1, Wkb, (void*)St, C_, C_, sCC, 0, sCC, uu, bk, bv, wwv, nullptr);

    // 6. h = St.bq ; HT[c,i] = sum_c' St[c,c'] WqT[i,c']
    compute_h_kernel<<<dim3(B_), blk, 0, stream>>>(St, bq, hb);
    gemm_nt2<0><<<dim3(C_ / 128, C_ / 128, B_), blk, 0, stream>>>(
        St, WqTb, (void*)HT, C_, C_, sCC, 0, sCC, nullptr, nullptr, nullptr, nullptr, nullptr);

    // 7. out[c,n] = sum_i HT[c,i] qT[n,i] + h[b][c] + q[c,n]  (fp32 final)
    gemm_nt2<2><<<dim3(N_ / 128, C_ / 128, B_), blk, 0, stream>>>(
        HT, qT, (void*)out, N_, C_, sCC, sBN, sBN, hb, nullptr, nullptr, nullptr, q);
}

// Round 8
// 151.425 us; speedup vs baseline: 1.1795x; 1.1795x over previous
//
#include <hip/hip_runtime.h>
#include <hip/hip_bf16.h>
#include <stdint.h>

#define B_ 8
#define C_ 512
#define N_ 2048

typedef __bf16 bf16_t;
typedef bf16_t bf16x8 __attribute__((ext_vector_type(8)));
typedef bf16_t bf16x4 __attribute__((ext_vector_type(4)));
typedef float f32x4 __attribute__((ext_vector_type(4)));

// ---------------------------------------------------------------------------
// Cast two 512x512 weight matrices to bf16 (Wk, Wv -> contiguous).
// ---------------------------------------------------------------------------
__global__ __launch_bounds__(256) void cast_w_kernel(
    const float* __restrict__ w0, const float* __restrict__ w1,
    bf16_t* __restrict__ out)
{
    const float* src = (blockIdx.z == 0) ? w0 : w1;
    bf16_t* dst = out + (size_t)blockIdx.z * (C_ * C_);
    int i = (blockIdx.x * 256 + threadIdx.x) * 4;
    float4 f = *(const float4*)(src + i);
    bf16x4 o;
    o[0] = (bf16_t)f.x; o[1] = (bf16_t)f.y; o[2] = (bf16_t)f.z; o[3] = (bf16_t)f.w;
    *(bf16x4*)(dst + i) = o;
}

// ---------------------------------------------------------------------------
// Transpose-cast Wq: fp32 [C][C] -> bf16 out[i][c] = in[c][i]. grid (8,8).
// ---------------------------------------------------------------------------
__global__ __launch_bounds__(256) void transpose_cast_w_kernel(
    const float* __restrict__ in, bf16_t* __restrict__ out)
{
    __shared__ bf16_t tile[64][65];
    const int i0 = blockIdx.x * 64;
    const int c0 = blockIdx.y * 64;
    const int t = threadIdx.x;
    const int cx = (t & 15) * 4;
    const int ry = t >> 4;
#pragma unroll
    for (int r = ry; r < 64; r += 16) {
        float4 f = *(const float4*)&in[(size_t)(c0 + r) * C_ + i0 + cx];
        tile[r][cx + 0] = (bf16_t)f.x;
        tile[r][cx + 1] = (bf16_t)f.y;
        tile[r][cx + 2] = (bf16_t)f.z;
        tile[r][cx + 3] = (bf16_t)f.w;
    }
    __syncthreads();
    const int c4 = (t & 15) * 4;
    const int rb = t >> 4;
#pragma unroll
    for (int r = rb; r < 64; r += 16) {
        bf16x4 o;
        o[0] = tile[c4 + 0][r];
        o[1] = tile[c4 + 1][r];
        o[2] = tile[c4 + 2][r];
        o[3] = tile[c4 + 3][r];
        *(bf16x4*)&out[(size_t)(i0 + r) * C_ + c0 + c4] = o;
    }
}

// ---------------------------------------------------------------------------
// Transpose-cast: fp32 [B][C][N] -> bf16 [B][N][C]. grid (N/64, C/64, B).
// (r1-proven; used for q.)
// ---------------------------------------------------------------------------
__global__ __launch_bounds__(256) void transpose_cast_kernel(
    const float* __restrict__ in, bf16_t* __restrict__ out)
{
    __shared__ bf16_t tile[64][65];
    const int b = blockIdx.z;
    const float* src = in + (size_t)b * C_ * N_;
    bf16_t* dst = out + (size_t)b * N_ * C_;
    const int n0 = blockIdx.x * 64;
    const int c0 = blockIdx.y * 64;
    const int t = threadIdx.x;
    const int cx = (t & 15) * 4;
    const int ry = t >> 4;
#pragma unroll
    for (int r = ry; r < 64; r += 16) {
        float4 f = *(const float4*)&src[(size_t)(c0 + r) * N_ + n0 + cx];
        tile[r][cx + 0] = (bf16_t)f.x;
        tile[r][cx + 1] = (bf16_t)f.y;
        tile[r][cx + 2] = (bf16_t)f.z;
        tile[r][cx + 3] = (bf16_t)f.w;
    }
    __syncthreads();
    const int c4 = (t & 15) * 4;
    const int rb = t >> 4;
#pragma unroll
    for (int r = rb; r < 64; r += 16) {
        bf16x4 o;
        o[0] = tile[c4 + 0][r];
        o[1] = tile[c4 + 1][r];
        o[2] = tile[c4 + 2][r];
        o[3] = tile[c4 + 3][r];
        *(bf16x4*)&dst[(size_t)(n0 + r) * C_ + c0 + c4] = o;
    }
}

// ---------------------------------------------------------------------------
// cast_kv: k,v fp32 [B][C][N] -> bf16 (same layout) + per-row sums.
// grid (B*C, 2): block = one row of one tensor; 256 thr x 8 elems = 2048.
// sk[row] = sum_n k[row,n] (fp32, exact from source regs). No atomics.
// ---------------------------------------------------------------------------
__global__ __launch_bounds__(256) void cast_kv_kernel(
    const float* __restrict__ kin, const float* __restrict__ vin,
    bf16_t* __restrict__ kc, bf16_t* __restrict__ vc,
    float* __restrict__ sk, float* __restrict__ sv)
{
    __shared__ float red[4];
    const int row = blockIdx.x;           // b*C + c
    const int selv = blockIdx.y;
    const float* src = (selv ? vin : kin) + (size_t)row * N_;
    bf16_t* dst = (selv ? vc : kc) + (size_t)row * N_;
    const int i = threadIdx.x * 8;
    float4 f0 = *(const float4*)(src + i);
    float4 f1 = *(const float4*)(src + i + 4);
    bf16x8 o;
    o[0] = (bf16_t)f0.x; o[1] = (bf16_t)f0.y; o[2] = (bf16_t)f0.z; o[3] = (bf16_t)f0.w;
    o[4] = (bf16_t)f1.x; o[5] = (bf16_t)f1.y; o[6] = (bf16_t)f1.z; o[7] = (bf16_t)f1.w;
    *(bf16x8*)(dst + i) = o;
    float s = f0.x + f0.y + f0.z + f0.w + f1.x + f1.y + f1.z + f1.w;
#pragma unroll
    for (int d = 1; d < 64; d <<= 1) s += __shfl_xor(s, d, 64);
    if ((threadIdx.x & 63) == 0) red[threadIdx.x >> 6] = s;
    __syncthreads();
    if (threadIdx.x == 0)
        (selv ? sv : sk)[row] = red[0] + red[1] + red[2] + red[3];
}

// ---------------------------------------------------------------------------
// Split-K NT bf16 GEMM (r2/r6-proven): C[m,n] = sum_k A[m,k]*B[n,k], bf16 out.
// Single-buffer, 2 barriers/K-step, global_load_lds both sides with source
// chunk pre-swizzle + swizzled conflict-free reads. blockIdx.z = b*SPLITS+sp.
// ---------------------------------------------------------------------------
template <int SPLITS>
__global__ __launch_bounds__(256, 2) void gemm_ntK(
    const bf16_t* __restrict__ A, const bf16_t* __restrict__ Bm,
    bf16_t* __restrict__ Cout,
    int Nn, int K, size_t sA, size_t sB, size_t sC)
{
    __shared__ __align__(16) bf16_t As[128 * 64];
    __shared__ __align__(16) bf16_t Bs[128 * 64];

    const int tid = threadIdx.x, lane = tid & 63, wave = tid >> 6;
    const int wr = wave >> 1, wc = wave & 1;
    const int bz = blockIdx.z / SPLITS;
    const int sp = blockIdx.z % SPLITS;
    const int kbeg = sp * (K / SPLITS);
    const int nt = (K / SPLITS) / 64;

    const bf16_t* Ab = A + (size_t)bz * sA;
    const bf16_t* Bb = Bm + (size_t)bz * sB;
    const int m0 = blockIdx.y * 128, n0 = blockIdx.x * 128;

    f32x4 acc[4][4];
#pragma unroll
    for (int i = 0; i < 4; ++i)
#pragma unroll
        for (int j = 0; j < 4; ++j) acc[i][j] = 0.f;

    const int srow = tid >> 3;
    const int scol = ((tid & 7) ^ (srow & 7)) * 8;
    const int ldso = tid * 16;

    for (int t = 0; t < nt; ++t) {
        const bf16_t* ga = Ab + (size_t)(m0 + srow) * K + kbeg + t * 64 + scol;
        const bf16_t* gb = Bb + (size_t)(n0 + srow) * K + kbeg + t * 64 + scol;
#pragma unroll
        for (int p = 0; p < 4; ++p)
            __builtin_amdgcn_global_load_lds(
                (const __attribute__((address_space(1))) void*)(ga + (size_t)p * 32 * K),
                (__attribute__((address_space(3))) void*)((char*)As + ldso + p * 4096),
                16, 0, 0);
#pragma unroll
        for (int p = 0; p < 4; ++p)
            __builtin_amdgcn_global_load_lds(
                (const __attribute__((address_space(1))) void*)(gb + (size_t)p * 32 * K),
                (__attribute__((address_space(3))) void*)((char*)Bs + ldso + p * 4096),
                16, 0, 0);
        __syncthreads();

#pragma unroll
        for (int kk = 0; kk < 64; kk += 32) {
            bf16x8 af[4], bfr[4];
            const int kcol = kk + (lane >> 4) * 8;
            const int kc = kcol >> 3;
#pragma unroll
            for (int m = 0; m < 4; ++m) {
                const int r = wr * 64 + (lane & 15) + m * 16;
                af[m] = *(const bf16x8*)((const char*)As + r * 128 +
                                         ((kc ^ (r & 7)) << 4));
            }
#pragma unroll
            for (int n = 0; n < 4; ++n) {
                const int r = wc * 64 + (lane & 15) + n * 16;
                bfr[n] = *(const bf16x8*)((const char*)Bs + r * 128 +
                                          ((kc ^ (r & 7)) << 4));
            }
#pragma unroll
            for (int m = 0; m < 4; ++m)
#pragma unroll
                for (int n = 0; n < 4; ++n)
                    acc[m][n] = __builtin_amdgcn_mfma_f32_16x16x32_bf16(
                        af[m], bfr[n], acc[m][n], 0, 0, 0);
        }
        __syncthreads();
    }

    const int rj = (lane >> 4) * 4;
    const int cc = lane & 15;
#pragma unroll
    for (int m = 0; m < 4; ++m) {
#pragma unroll
        for (int n = 0; n < 4; ++n) {
            const int col = n0 + wc * 64 + n * 16 + cc;
            f32x4 vv = acc[m][n];
#pragma unroll
            for (int j = 0; j < 4; ++j) {
                const int row = m0 + wr * 64 + m * 16 + rj + j;
                Cout[(size_t)blockIdx.z * sC + (size_t)row * Nn + col] = (bf16_t)vv[j];
            }
        }
    }
}

// ---------------------------------------------------------------------------
// Sum 4 split-K bf16 partials -> bf16. Pt: [B_][4][C_*C_], Out: [B_][C_*C_].
// ---------------------------------------------------------------------------
__global__ __launch_bounds__(256) void reduce_splitk_kernel(
    const bf16_t* __restrict__ Pt, bf16_t* __restrict__ Out)
{
    const size_t sCC = (size_t)C_ * C_;
    size_t idx = ((size_t)blockIdx.x * 256 + threadIdx.x) * 8;
    size_t b = idx / sCC;
    size_t r = idx - b * sCC;
    const bf16_t* base = Pt + (b * 4) * sCC + r;
    float acc[8];
#pragma unroll
    for (int j = 0; j < 8; ++j) acc[j] = 0.f;
#pragma unroll
    for (int s = 0; s < 4; ++s) {
        bf16x8 pv = *(const bf16x8*)(base + (size_t)s * sCC);
#pragma unroll
        for (int j = 0; j < 8; ++j) acc[j] += (float)pv[j];
    }
    bf16x8 o;
#pragma unroll
    for (int j = 0; j < 8; ++j) o[j] = (bf16_t)acc[j];
    *(bf16x8*)(Out + idx) = o;
}

// ---------------------------------------------------------------------------
// 64x64-tile NT bf16 GEMM for the C^3 chain (fills 512 blocks at C=512).
// K fixed 512. Same swizzled global_load_lds scheme, 2 passes of 32 rows.
// EPI 0: bf16 out.  EPI 1: bf16 out + rank-1 (St epilogue).
// ---------------------------------------------------------------------------
template <int EPI>
__global__ __launch_bounds__(256) void gemm64_nt(
    const bf16_t* __restrict__ A, const bf16_t* __restrict__ Bm,
    bf16_t* __restrict__ Cout, size_t sA, size_t sB, size_t sC,
    const float* __restrict__ e0, const float* __restrict__ e1,
    const float* __restrict__ e2, const float* __restrict__ e3)
{
    __shared__ __align__(16) bf16_t As[64 * 64];   // 8 KB
    __shared__ __align__(16) bf16_t Bs[64 * 64];

    const int tid = threadIdx.x, lane = tid & 63, wave = tid >> 6;
    const int wr = wave >> 1, wc = wave & 1;
    const int bz = blockIdx.z;
    const int m0 = blockIdx.y * 64, n0 = blockIdx.x * 64;
    const int K = C_;

    const bf16_t* Ab = A + (size_t)bz * sA;
    const bf16_t* Bb = Bm + (size_t)bz * sB;

    f32x4 acc[2][2];
#pragma unroll
    for (int i = 0; i < 2; ++i)
#pragma unroll
        for (int j = 0; j < 2; ++j) acc[i][j] = 0.f;

    const int srow = tid >> 3;                       // 0..31
    const int scol = ((tid & 7) ^ (srow & 7)) * 8;   // swizzled chunk
    const int ldso = tid * 16;                       // +p*4096 (32 rows)

    for (int t = 0; t < 8; ++t) {
        const bf16_t* ga = Ab + (size_t)(m0 + srow) * K + t * 64 + scol;
        const bf16_t* gb = Bb + (size_t)(n0 + srow) * K + t * 64 + scol;
#pragma unroll
        for (int p = 0; p < 2; ++p)
            __builtin_amdgcn_global_load_lds(
                (const __attribute__((address_space(1))) void*)(ga + (size_t)p * 32 * K),
                (__attribute__((address_space(3))) void*)((char*)As + ldso + p * 4096),
                16, 0, 0);
#pragma unroll
        for (int p = 0; p < 2; ++p)
            __builtin_amdgcn_global_load_lds(
                (const __attribute__((address_space(1))) void*)(gb + (size_t)p * 32 * K),
                (__attribute__((address_space(3))) void*)((char*)Bs + ldso + p * 4096),
                16, 0, 0);
        __syncthreads();

#pragma unroll
        for (int kk = 0; kk < 64; kk += 32) {
            bf16x8 af[2], bfr[2];
            const int kcol = kk + (lane >> 4) * 8;
            const int kc = kcol >> 3;
#pragma unroll
            for (int m = 0; m < 2; ++m) {
                const int r = wr * 32 + (lane & 15) + m * 16;
                af[m] = *(const bf16x8*)((const char*)As + r * 128 +
                                         ((kc ^ (r & 7)) << 4));
            }
#pragma unroll
            for (int n = 0; n < 2; ++n) {
                const int r = wc * 32 + (lane & 15) + n * 16;
                bfr[n] = *(const bf16x8*)((const char*)Bs + r * 128 +
                                          ((kc ^ (r & 7)) << 4));
            }
#pragma unroll
            for (int m = 0; m < 2; ++m)
#pragma unroll
                for (int n = 0; n < 2; ++n)
                    acc[m][n] = __builtin_amdgcn_mfma_f32_16x16x32_bf16(
                        af[m], bfr[n], acc[m][n], 0, 0, 0);
        }
        __syncthreads();
    }

    const int rj = (lane >> 4) * 4;
    const int cc = lane & 15;
#pragma unroll
    for (int m = 0; m < 2; ++m) {
#pragma unroll
        for (int n = 0; n < 2; ++n) {
            const int col = n0 + wc * 32 + n * 16 + cc;
            f32x4 vv = acc[m][n];
#pragma unroll
            for (int j = 0; j < 4; ++j) {
                const int row = m0 + wr * 32 + m * 16 + rj + j;
                float val = vv[j];
                if (EPI == 1)
                    val += e0[bz * C_ + row] * e1[col] +
                           e2[row] * (e3[bz * C_ + col] + 2048.0f * e1[col]);
                Cout[(size_t)bz * sC + (size_t)row * C_ + col] = (bf16_t)val;
            }
        }
    }
}

// ---------------------------------------------------------------------------
// Final GEMM (r7-proven): out[c,n] = sum_i HT[c,i]*qT[n,i] + h[b][c] + q[c,n].
// fp32 out, 128-tile, global_load_lds both sides.
// ---------------------------------------------------------------------------
__global__ __launch_bounds__(256) void gemm_final(
    const bf16_t* __restrict__ A, const bf16_t* __restrict__ Bm,
    float* __restrict__ Cout, int Nn, int K, size_t sA, size_t sB, size_t sC,
    const float* __restrict__ e0, const float* __restrict__ resid)
{
    __shared__ __align__(16) bf16_t As[128 * 64];
    __shared__ __align__(16) bf16_t Bs[128 * 64];

    const int tid = threadIdx.x, lane = tid & 63, wave = tid >> 6;
    const int wr = wave >> 1, wc = wave & 1;
    const int bz = blockIdx.z;
    const bf16_t* Ab = A + (size_t)bz * sA;
    const bf16_t* Bb = Bm + (size_t)bz * sB;
    const int m0 = blockIdx.y * 128, n0 = blockIdx.x * 128;

    f32x4 acc[4][4];
#pragma unroll
    for (int i = 0; i < 4; ++i)
#pragma unroll
        for (int j = 0; j < 4; ++j) acc[i][j] = 0.f;

    const int srow = tid >> 3;
    const int scol = ((tid & 7) ^ (srow & 7)) * 8;
    const int ldso = tid * 16;
    const int nt = K / 64;

    for (int t = 0; t < nt; ++t) {
        const bf16_t* ga = Ab + (size_t)(m0 + srow) * K + t * 64 + scol;
        const bf16_t* gb = Bb + (size_t)(n0 + srow) * K + t * 64 + scol;
#pragma unroll
        for (int p = 0; p < 4; ++p)
            __builtin_amdgcn_global_load_lds(
                (const __attribute__((address_space(1))) void*)(ga + (size_t)p * 32 * K),
                (__attribute__((address_space(3))) void*)((char*)As + ldso + p * 4096),
                16, 0, 0);
#pragma unroll
        for (int p = 0; p < 4; ++p)
            __builtin_amdgcn_global_load_lds(
                (const __attribute__((address_space(1))) void*)(gb + (size_t)p * 32 * K),
                (__attribute__((address_space(3))) void*)((char*)Bs + ldso + p * 4096),
                16, 0, 0);
        __syncthreads();

#pragma unroll
        for (int kk = 0; kk < 64; kk += 32) {
            bf16x8 af[4], bfr[4];
            const int kcol = kk + (lane >> 4) * 8;
            const int kc = kcol >> 3;
#pragma unroll
            for (int m = 0; m < 4; ++m) {
                const int r = wr * 64 + (lane & 15) + m * 16;
                af[m] = *(const bf16x8*)((const char*)As + r * 128 +
                                         ((kc ^ (r & 7)) << 4));
            }
#pragma unroll
            for (int n = 0; n < 4; ++n) {
                const int r = wc * 64 + (lane & 15) + n * 16;
                bfr[n] = *(const bf16x8*)((const char*)Bs + r * 128 +
                                          ((kc ^ (r & 7)) << 4));
            }
#pragma unroll
            for (int m = 0; m < 4; ++m)
#pragma unroll
                for (int n = 0; n < 4; ++n)
                    acc[m][n] = __builtin_amdgcn_mfma_f32_16x16x32_bf16(
                        af[m], bfr[n], acc[m][n], 0, 0, 0);
        }
        __syncthreads();
    }

    const int rj = (lane >> 4) * 4;
    const int cc = lane & 15;
#pragma unroll
    for (int m = 0; m < 4; ++m) {
#pragma unroll
        for (int n = 0; n < 4; ++n) {
            const int col = n0 + wc * 64 + n * 16 + cc;
            f32x4 vv = acc[m][n];
#pragma unroll
            for (int j = 0; j < 4; ++j) {
                const int row = m0 + wr * 64 + m * 16 + rj + j;
                const size_t o = (size_t)bz * sC + (size_t)row * Nn + col;
                Cout[o] = vv[j] + e0[bz * C_ + row] + resid[o];
            }
        }
    }
}

// ---------------------------------------------------------------------------
// u[b] = Wvb . sv[b],  w[b] = Wkb . sk[b].  grid (2*B_).
// ---------------------------------------------------------------------------
__global__ __launch_bounds__(256) void matvec_uw_kernel(
    const bf16_t* __restrict__ Wvb, const bf16_t* __restrict__ Wkb,
    const float* __restrict__ sv, const float* __restrict__ sk,
    float* __restrict__ u, float* __restrict__ w)
{
    const int b2 = blockIdx.x;
    const int b = b2 >> 1, sel = b2 & 1;
    const bf16_t* W = sel ? Wkb : Wvb;
    const float* s  = (sel ? sk : sv) + (size_t)b * C_;
    float* o        = (sel ? w : u) + (size_t)b * C_;
    const int c = threadIdx.x * 2;
#pragma unroll
    for (int rr = 0; rr < 2; ++rr) {
        const bf16_t* row = W + (size_t)(c + rr) * C_;
        float acc = 0.f;
        for (int j = 0; j < C_; j += 8) {
            bf16x8 vv = *(const bf16x8*)(row + j);
#pragma unroll
            for (int t = 0; t < 8; ++t) acc += (float)vv[t] * s[j + t];
        }
        o[c + rr] = acc;
    }
}

// ---------------------------------------------------------------------------
// h[b][c] = sum_c1 St[b][c,c1] * bq[c1].
// ---------------------------------------------------------------------------
__global__ __launch_bounds__(256) void compute_h_kernel(
    const bf16_t* __restrict__ St, const float* __restrict__ bq,
    float* __restrict__ h)
{
    const int b = blockIdx.x;
    const int c = threadIdx.x * 2;
#pragma unroll
    for (int rr = 0; rr < 2; ++rr) {
        const bf16_t* row = St + ((size_t)b * C_ + c + rr) * C_;
        float acc = 0.f;
        for (int j = 0; j < C_; j += 8) {
            bf16x8 vv = *(const bf16x8*)(row + j);
#pragma unroll
            for (int t = 0; t < 8; ++t) acc += (float)vv[t] * bq[j + t];
        }
        h[b * C_ + c + rr] = acc;
    }
}

// ---------------------------------------------------------------------------
extern "C" void kernel_launch(void* const* d_in, const int* in_sizes, int n_in,
                              void* d_out, int out_size, void* d_ws, size_t ws_size,
                              hipStream_t stream)
{
    (void)in_sizes; (void)n_in; (void)out_size; (void)ws_size;
    const float* q  = (const float*)d_in[0];
    const float* k  = (const float*)d_in[1];
    const float* v  = (const float*)d_in[2];
    const float* wq = (const float*)d_in[3];
    const float* bq = (const float*)d_in[4];
    const float* wk = (const float*)d_in[5];
    const float* bk = (const float*)d_in[6];
    const float* wv = (const float*)d_in[7];
    const float* bv = (const float*)d_in[8];
    float* out = (float*)d_out;

    char* ws = (char*)d_ws;
    const size_t WSZ = (size_t)C_ * C_ * 2;            // 512 KB
    const size_t TSZ = (size_t)B_ * N_ * C_ * 2;       // 16.78 MB
    const size_t SCZ = (size_t)B_ * C_ * C_ * 2;       // 4.19 MB
    const size_t VSZ = (size_t)B_ * C_ * 4;            // 16 KB
    size_t off = 0;
    bf16_t* Wkb  = (bf16_t*)(ws + off); off += WSZ;
    bf16_t* Wvb  = (bf16_t*)(ws + off); off += WSZ;
    bf16_t* WqTb = (bf16_t*)(ws + off); off += WSZ;
    bf16_t* kc   = (bf16_t*)(ws + off); off += TSZ;
    bf16_t* vc   = (bf16_t*)(ws + off); off += TSZ;
    bf16_t* DpqT = (bf16_t*)(ws + off); off += TSZ;    // Dp (splitK partials),
    bf16_t* Dp   = DpqT;                               //  then reused as qT
    bf16_t* qT   = DpqT;
    bf16_t* D    = (bf16_t*)(ws + off); off += SCZ;
    bf16_t* P1   = (bf16_t*)(ws + off); off += SCZ;
    bf16_t* St   = (bf16_t*)(ws + off); off += SCZ;
    bf16_t* HT   = (bf16_t*)(ws + off); off += SCZ;
    float*  sk   = (float*)(ws + off);  off += VSZ;
    float*  sv   = (float*)(ws + off);  off += VSZ;
    float*  uu   = (float*)(ws + off);  off += VSZ;
    float*  wwv  = (float*)(ws + off);  off += VSZ;
    float*  hb   = (float*)(ws + off);  off += VSZ;

    const dim3 blk(256);
    const size_t sBN = (size_t)N_ * C_;
    const size_t sCC = (size_t)C_ * C_;

    // 1. weights: Wk,Wv -> bf16; WqT = Wq^T bf16
    cast_w_kernel<<<dim3(256, 1, 2), blk, 0, stream>>>(wk, wv, Wkb);
    transpose_cast_w_kernel<<<dim3(C_ / 64, C_ / 64), blk, 0, stream>>>(wq, WqTb);

    // 2. k,v -> bf16 (same layout) + row sums sk,sv
    cast_kv_kernel<<<dim3(B_ * C_, 2), blk, 0, stream>>>(k, v, kc, vc, sk, sv);

    // 3. D[i,j] = sum_n kc[i,n] vc[j,n]  (split-K 4 + reduce)
    gemm_ntK<4><<<dim3(C_ / 128, C_ / 128, B_ * 4), blk, 0, stream>>>(
        kc, vc, Dp, C_, N_, sBN, sBN, sCC);
    reduce_splitk_kernel<<<dim3((B_ * sCC) / (256 * 8)), blk, 0, stream>>>(Dp, D);

    // 4. qT = q^T bf16 [B,N,C]  (Dp is dead now; same buffer)
    transpose_cast_kernel<<<dim3(N_ / 64, C_ / 64, B_), blk, 0, stream>>>(q, qT);

    // 5. u = Wv.sv, w = Wk.sk
    matvec_uw_kernel<<<dim3(2 * B_), blk, 0, stream>>>(Wvb, Wkb, sv, sk, uu, wwv);

    // 6. P1[c2,i] = sum_j Wv[c2,j] D[i,j]   (64-tile, 512 blocks)
    gemm64_nt<0><<<dim3(C_ / 64, C_ / 64, B_), blk, 0, stream>>>(
        Wvb, D, P1, 0, sCC, sCC, nullptr, nullptr, nullptr, nullptr);

    // 7. St[c2,c1] = sum_i P1[c2,i] Wk[c1,i] + u[c2]bk[c1] + bv[c2](w[c1]+N bk[c1])
    gemm64_nt<1><<<dim3(C_ / 64, C_ / 64, B_), blk, 0, stream>>>(
        P1, Wkb, St, sCC, 0, sCC, uu, bk, bv, wwv);

    // 8. h = St.bq ; HT[c,i] = sum_c' St[c,c'] WqT[i,c']
    compute_h_kernel<<<dim3(B_), blk, 0, stream>>>(St, bq, hb);
    gemm64_nt<0><<<dim3(C_ / 64, C_ / 64, B_), blk, 0, stream>>>(
        St, WqTb, HT, sCC, 0, sCC, nullptr, nullptr, nullptr, nullptr);

    // 9. out[c,n] = sum_i HT[c,i] qT[n,i] + h[b][c] + q[c,n]  (fp32 final)
    gemm_final<<<dim3(N_ / 128, C_ / 128, B_), blk, 0, stream>>>(
        HT, qT, out, N_, C_, sCC, sBN, sBN, hb, q);
}

// Round 9
// 108.851 us; speedup vs baseline: 1.6408x; 1.3911x over previous
//
#include <hip/hip_runtime.h>
#include <hip/hip_bf16.h>
#include <stdint.h>

#define B_ 8
#define C_ 512
#define N_ 2048

typedef __bf16 bf16_t;
typedef bf16_t bf16x8 __attribute__((ext_vector_type(8)));
typedef bf16_t bf16x4 __attribute__((ext_vector_type(4)));
typedef float f32x4 __attribute__((ext_vector_type(4)));

// ---------------------------------------------------------------------------
// weights_kernel (1 dispatch): blocks 0..63 transpose-cast Wq (64x64 tiles),
// blocks 64..127 cast Wk, blocks 128..191 cast Wv.
// ---------------------------------------------------------------------------
__global__ __launch_bounds__(256) void weights_kernel(
    const float* __restrict__ wq, const float* __restrict__ wk,
    const float* __restrict__ wv, bf16_t* __restrict__ WqT,
    bf16_t* __restrict__ Wkb, bf16_t* __restrict__ Wvb)
{
    __shared__ bf16_t tile[64][65];
    const int t = blockIdx.x;
    const int tid = threadIdx.x;
    if (t < 64) {
        const int i0 = (t & 7) * 64, c0 = (t >> 3) * 64;
        const int cx = (tid & 15) * 4, ry = tid >> 4;
#pragma unroll
        for (int r = ry; r < 64; r += 16) {
            float4 f = *(const float4*)&wq[(size_t)(c0 + r) * C_ + i0 + cx];
            tile[r][cx + 0] = (bf16_t)f.x; tile[r][cx + 1] = (bf16_t)f.y;
            tile[r][cx + 2] = (bf16_t)f.z; tile[r][cx + 3] = (bf16_t)f.w;
        }
        __syncthreads();
#pragma unroll
        for (int r = ry; r < 64; r += 16) {
            bf16x4 o;
            o[0] = tile[cx + 0][r]; o[1] = tile[cx + 1][r];
            o[2] = tile[cx + 2][r]; o[3] = tile[cx + 3][r];
            *(bf16x4*)&WqT[(size_t)(i0 + r) * C_ + c0 + cx] = o;
        }
    } else {
        int j = t - 64;
        const float* src = (j < 64) ? wk : wv;
        bf16_t* dst = (j < 64) ? Wkb : Wvb;
        j &= 63;
#pragma unroll
        for (int p = 0; p < 4; ++p) {
            const int i = j * 4096 + p * 1024 + tid * 4;
            float4 f = *(const float4*)(src + i);
            bf16x4 o;
            o[0] = (bf16_t)f.x; o[1] = (bf16_t)f.y;
            o[2] = (bf16_t)f.z; o[3] = (bf16_t)f.w;
            *(bf16x4*)(dst + i) = o;
        }
    }
}

// ---------------------------------------------------------------------------
// prep_q: q fp32 [B][C][N] -> qT bf16 [B][N][C]  AND  qc bf16 [B][C][N].
// grid (N/64, C/64, B). (r1-proven transpose + extra coalesced qc store.)
// ---------------------------------------------------------------------------
__global__ __launch_bounds__(256) void prep_q_kernel(
    const float* __restrict__ q, bf16_t* __restrict__ qT, bf16_t* __restrict__ qc)
{
    __shared__ bf16_t tile[64][65];
    const int b = blockIdx.z;
    const float* src = q + (size_t)b * C_ * N_;
    bf16_t* dT = qT + (size_t)b * N_ * C_;
    bf16_t* dc = qc + (size_t)b * C_ * N_;
    const int n0 = blockIdx.x * 64, c0 = blockIdx.y * 64;
    const int t = threadIdx.x;
    const int cx = (t & 15) * 4, ry = t >> 4;
#pragma unroll
    for (int r = ry; r < 64; r += 16) {
        float4 f = *(const float4*)&src[(size_t)(c0 + r) * N_ + n0 + cx];
        bf16x4 o;
        o[0] = (bf16_t)f.x; o[1] = (bf16_t)f.y;
        o[2] = (bf16_t)f.z; o[3] = (bf16_t)f.w;
        tile[r][cx + 0] = o[0]; tile[r][cx + 1] = o[1];
        tile[r][cx + 2] = o[2]; tile[r][cx + 3] = o[3];
        *(bf16x4*)&dc[(size_t)(c0 + r) * N_ + n0 + cx] = o;
    }
    __syncthreads();
#pragma unroll
    for (int r = ry; r < 64; r += 16) {
        bf16x4 o;
        o[0] = tile[cx + 0][r]; o[1] = tile[cx + 1][r];
        o[2] = tile[cx + 2][r]; o[3] = tile[cx + 3][r];
        *(bf16x4*)&dT[(size_t)(n0 + r) * C_ + c0 + cx] = o;
    }
}

// ---------------------------------------------------------------------------
// gemm_dkv: Dp[b*4+sp][i,j] = sum_{n in split sp} k[b,i,n]*v[b,j,n].
// Reads fp32 k,v DIRECTLY via global_load_lds (DMA path; no cast round-trip).
// LDS tiles are fp32 (2x32 KB, 2 blocks/CU), chunk-swizzled (16B chunk,
// slot = c ^ (r&7)); fragments read as 2x f32x4 then converted to bf16 regs.
// Proven 2-barrier sync. sk4/sv4 per-split row sums computed from the staged
// LDS tiles by n0==0 / m0==0 blocks (no atomics: layout [sp][B][C]).
// 1-D swizzled grid (512): 16 blocks of one (b,sp) share an XCD.
// ---------------------------------------------------------------------------
__global__ __launch_bounds__(256) void gemm_dkv(
    const float* __restrict__ Kin, const float* __restrict__ Vin,
    bf16_t* __restrict__ Dp, float* __restrict__ sk4, float* __restrict__ sv4)
{
    __shared__ __align__(16) float As[128 * 64];   // 32 KB
    __shared__ __align__(16) float Bs[128 * 64];   // 32 KB

    const int f = blockIdx.x;
    const int xcd = f & 7, sl = f >> 3;
    const int g = xcd + 8 * (sl >> 4), t5 = sl & 15;   // g in [0,32)
    const int bz = g >> 2, sp = g & 3;
    const int m0 = (t5 >> 2) * 128, n0 = (t5 & 3) * 128;
    const int kbeg = sp * 512;

    const int tid = threadIdx.x, lane = tid & 63, wave = tid >> 6;
    const int wr = wave >> 1, wc = wave & 1;

    const float* Ab = Kin + (size_t)bz * C_ * N_;
    const float* Bb = Vin + (size_t)bz * C_ * N_;

    f32x4 acc[4][4];
#pragma unroll
    for (int i = 0; i < 4; ++i)
#pragma unroll
        for (int j = 0; j < 4; ++j) acc[i][j] = 0.f;

    // staging: pass p covers rows p*16+(tid>>4); dest linear tid*16+p*4096;
    // source chunk = (tid&15) ^ ((tid>>4)&7)  [slot s holds chunk s^(r&7)]
    const int prow = tid >> 4;
    const int cs   = (tid & 15) ^ (prow & 7);
    const int ldso = tid * 16;

    // row-sum state (2 threads per row, staggered slots -> no hot bank)
    const int srr = tid >> 1, hh = tid & 1;
    float hsA = 0.f, hsB = 0.f;
    const bool doA = (n0 == 0), doB = (m0 == 0);

    for (int t = 0; t < 8; ++t) {
        const float* ga = Ab + (size_t)(m0 + prow) * N_ + kbeg + t * 64 + cs * 4;
        const float* gb = Bb + (size_t)(n0 + prow) * N_ + kbeg + t * 64 + cs * 4;
#pragma unroll
        for (int p = 0; p < 8; ++p)
            __builtin_amdgcn_global_load_lds(
                (const __attribute__((address_space(1))) void*)(ga + (size_t)p * 16 * N_),
                (__attribute__((address_space(3))) void*)((char*)As + ldso + p * 4096),
                16, 0, 0);
#pragma unroll
        for (int p = 0; p < 8; ++p)
            __builtin_amdgcn_global_load_lds(
                (const __attribute__((address_space(1))) void*)(gb + (size_t)p * 16 * N_),
                (__attribute__((address_space(3))) void*)((char*)Bs + ldso + p * 4096),
                16, 0, 0);
        __syncthreads();

#pragma unroll
        for (int kk = 0; kk < 64; kk += 32) {
            bf16x8 af[4], bfr[4];
            const int kcol = kk + (lane >> 4) * 8;
            const int c1 = kcol >> 2;                  // even chunk index
#pragma unroll
            for (int m = 0; m < 4; ++m) {
                const int r = wr * 64 + (lane & 15) + m * 16;
                f32x4 lo = *(const f32x4*)((const char*)As + r * 256 + ((c1 ^ (r & 7)) << 4));
                f32x4 hi = *(const f32x4*)((const char*)As + r * 256 + (((c1 + 1) ^ (r & 7)) << 4));
                bf16x8 fr;
                fr[0] = (bf16_t)lo[0]; fr[1] = (bf16_t)lo[1];
                fr[2] = (bf16_t)lo[2]; fr[3] = (bf16_t)lo[3];
                fr[4] = (bf16_t)hi[0]; fr[5] = (bf16_t)hi[1];
                fr[6] = (bf16_t)hi[2]; fr[7] = (bf16_t)hi[3];
                af[m] = fr;
            }
#pragma unroll
            for (int n = 0; n < 4; ++n) {
                const int r = wc * 64 + (lane & 15) + n * 16;
                f32x4 lo = *(const f32x4*)((const char*)Bs + r * 256 + ((c1 ^ (r & 7)) << 4));
                f32x4 hi = *(const f32x4*)((const char*)Bs + r * 256 + (((c1 + 1) ^ (r & 7)) << 4));
                bf16x8 fr;
                fr[0] = (bf16_t)lo[0]; fr[1] = (bf16_t)lo[1];
                fr[2] = (bf16_t)lo[2]; fr[3] = (bf16_t)lo[3];
                fr[4] = (bf16_t)hi[0]; fr[5] = (bf16_t)hi[1];
                fr[6] = (bf16_t)hi[2]; fr[7] = (bf16_t)hi[3];
                bfr[n] = fr;
            }
#pragma unroll
            for (int m = 0; m < 4; ++m)
#pragma unroll
                for (int n = 0; n < 4; ++n)
                    acc[m][n] = __builtin_amdgcn_mfma_f32_16x16x32_bf16(
                        af[m], bfr[n], acc[m][n], 0, 0, 0);
        }

        // row sums from staged tiles (between barriers; swizzle is a
        // within-row permutation so a full-row sum is order-agnostic)
        if (doA) {
#pragma unroll
            for (int u = 0; u < 8; ++u) {
                const int slot = ((hh * 8 + u) + srr) & 15;
                f32x4 vv = *(const f32x4*)((const char*)As + srr * 256 + slot * 16);
                hsA += vv[0] + vv[1] + vv[2] + vv[3];
            }
        }
        if (doB) {
#pragma unroll
            for (int u = 0; u < 8; ++u) {
                const int slot = ((hh * 8 + u) + srr) & 15;
                f32x4 vv = *(const f32x4*)((const char*)Bs + srr * 256 + slot * 16);
                hsB += vv[0] + vv[1] + vv[2] + vv[3];
            }
        }
        __syncthreads();
    }

    const int rj = (lane >> 4) * 4;
    const int cc = lane & 15;
    const size_t sCC = (size_t)C_ * C_;
    const int z = bz * 4 + sp;
#pragma unroll
    for (int m = 0; m < 4; ++m) {
#pragma unroll
        for (int n = 0; n < 4; ++n) {
            const int col = n0 + wc * 64 + n * 16 + cc;
            f32x4 vv = acc[m][n];
#pragma unroll
            for (int j = 0; j < 4; ++j) {
                const int row = m0 + wr * 64 + m * 16 + rj + j;
                Dp[(size_t)z * sCC + (size_t)row * C_ + col] = (bf16_t)vv[j];
            }
        }
    }
    if (doA) {
        hsA += __shfl_xor(hsA, 1, 64);
        if (!hh) sk4[(size_t)(sp * B_ + bz) * C_ + m0 + srr] = hsA;
    }
    if (doB) {
        hsB += __shfl_xor(hsB, 1, 64);
        if (!hh) sv4[(size_t)(sp * B_ + bz) * C_ + n0 + srr] = hsB;
    }
}

// ---------------------------------------------------------------------------
// reduce_mv: blocks 0..1023 sum the 4 split-K partials (Dp -> D);
// blocks 1024..1039 compute u[b] = Wv.(sum_sp sv4), w[b] = Wk.(sum_sp sk4).
// ---------------------------------------------------------------------------
__global__ __launch_bounds__(256) void reduce_mv_kernel(
    const bf16_t* __restrict__ Pt, bf16_t* __restrict__ Out,
    const bf16_t* __restrict__ Wvb, const bf16_t* __restrict__ Wkb,
    const float* __restrict__ sk4, const float* __restrict__ sv4,
    float* __restrict__ u, float* __restrict__ w)
{
    __shared__ float svec[C_];
    const size_t sCC = (size_t)C_ * C_;
    const int bid = blockIdx.x, tid = threadIdx.x;
    if (bid < 1024) {
        size_t idx = ((size_t)bid * 256 + tid) * 8;
        size_t b = idx / sCC;
        size_t r = idx - b * sCC;
        const bf16_t* base = Pt + (b * 4) * sCC + r;
        float acc[8];
#pragma unroll
        for (int j = 0; j < 8; ++j) acc[j] = 0.f;
#pragma unroll
        for (int s = 0; s < 4; ++s) {
            bf16x8 pv = *(const bf16x8*)(base + (size_t)s * sCC);
#pragma unroll
            for (int j = 0; j < 8; ++j) acc[j] += (float)pv[j];
        }
        bf16x8 o;
#pragma unroll
        for (int j = 0; j < 8; ++j) o[j] = (bf16_t)acc[j];
        *(bf16x8*)(Out + idx) = o;
    } else {
        const int b2 = bid - 1024, b = b2 >> 1, sel = b2 & 1;
        const float* s4 = (sel ? sk4 : sv4) + (size_t)b * C_;
        const size_t st = (size_t)B_ * C_;
#pragma unroll
        for (int rr = 0; rr < 2; ++rr) {
            const int j = tid * 2 + rr;
            svec[j] = s4[j] + s4[st + j] + s4[2 * st + j] + s4[3 * st + j];
        }
        __syncthreads();
        const bf16_t* W = sel ? Wkb : Wvb;
        float* o = (sel ? w : u) + (size_t)b * C_;
        const int c = tid * 2;
#pragma unroll
        for (int rr = 0; rr < 2; ++rr) {
            const bf16_t* row = W + (size_t)(c + rr) * C_;
            float acc = 0.f;
            for (int j = 0; j < C_; j += 8) {
                bf16x8 vv = *(const bf16x8*)(row + j);
#pragma unroll
                for (int e = 0; e < 8; ++e) acc += (float)vv[e] * svec[j + e];
            }
            o[c + rr] = acc;
        }
    }
}

// ---------------------------------------------------------------------------
// 64x64-tile NT bf16 GEMM (r8-proven). K = 512 fixed.
// EPI 0: bf16 out.  EPI 1: + rank-1 (St epilogue).
// EPI 2: bf16 out; blocks with blockIdx.x==0 also compute
//        hout[bz*C + m0 + r] = sum_c' A[m0+r, c'] * bqv[c']  (h = St.bq)
//        from the same LDS A-tiles (no extra HBM traffic).
// ---------------------------------------------------------------------------
template <int EPI>
__global__ __launch_bounds__(256) void gemm64_nt(
    const bf16_t* __restrict__ A, const bf16_t* __restrict__ Bm,
    bf16_t* __restrict__ Cout, size_t sA, size_t sB, size_t sC,
    const float* __restrict__ e0, const float* __restrict__ e1,
    const float* __restrict__ e2, const float* __restrict__ e3,
    const float* __restrict__ bqv, float* __restrict__ hout)
{
    __shared__ __align__(16) bf16_t As[64 * 64];   // 8 KB
    __shared__ __align__(16) bf16_t Bs[64 * 64];

    const int tid = threadIdx.x, lane = tid & 63, wave = tid >> 6;
    const int wr = wave >> 1, wc = wave & 1;
    const int bz = blockIdx.z;
    const int m0 = blockIdx.y * 64, n0 = blockIdx.x * 64;
    const int K = C_;

    const bf16_t* Ab = A + (size_t)bz * sA;
    const bf16_t* Bb = Bm + (size_t)bz * sB;

    f32x4 acc[2][2];
#pragma unroll
    for (int i = 0; i < 2; ++i)
#pragma unroll
        for (int j = 0; j < 2; ++j) acc[i][j] = 0.f;

    const int srow = tid >> 3;
    const int scol = ((tid & 7) ^ (srow & 7)) * 8;
    const int ldso = tid * 16;

    float hacc = 0.f;
    const bool doH = (EPI == 2) && (blockIdx.x == 0);

    for (int t = 0; t < 8; ++t) {
        const bf16_t* ga = Ab + (size_t)(m0 + srow) * K + t * 64 + scol;
        const bf16_t* gb = Bb + (size_t)(n0 + srow) * K + t * 64 + scol;
#pragma unroll
        for (int p = 0; p < 2; ++p)
            __builtin_amdgcn_global_load_lds(
                (const __attribute__((address_space(1))) void*)(ga + (size_t)p * 32 * K),
                (__attribute__((address_space(3))) void*)((char*)As + ldso + p * 4096),
                16, 0, 0);
#pragma unroll
        for (int p = 0; p < 2; ++p)
            __builtin_amdgcn_global_load_lds(
                (const __attribute__((address_space(1))) void*)(gb + (size_t)p * 32 * K),
                (__attribute__((address_space(3))) void*)((char*)Bs + ldso + p * 4096),
                16, 0, 0);
        __syncthreads();

#pragma unroll
        for (int kk = 0; kk < 64; kk += 32) {
            bf16x8 af[2], bfr[2];
            const int kcol = kk + (lane >> 4) * 8;
            const int kc = kcol >> 3;
#pragma unroll
            for (int m = 0; m < 2; ++m) {
                const int r = wr * 32 + (lane & 15) + m * 16;
                af[m] = *(const bf16x8*)((const char*)As + r * 128 +
                                         ((kc ^ (r & 7)) << 4));
            }
#pragma unroll
            for (int n = 0; n < 2; ++n) {
                const int r = wc * 32 + (lane & 15) + n * 16;
                bfr[n] = *(const bf16x8*)((const char*)Bs + r * 128 +
                                          ((kc ^ (r & 7)) << 4));
            }
#pragma unroll
            for (int m = 0; m < 2; ++m)
#pragma unroll
                for (int n = 0; n < 2; ++n)
                    acc[m][n] = __builtin_amdgcn_mfma_f32_16x16x32_bf16(
                        af[m], bfr[n], acc[m][n], 0, 0, 0);
        }
        if (doH) {
            const int rr = tid >> 2, qq = tid & 3;
#pragma unroll
            for (int u = 0; u < 2; ++u) {
                const int c = qq * 2 + u;
                bf16x8 av = *(const bf16x8*)((const char*)As + rr * 128 +
                                             ((c ^ (rr & 7)) << 4));
                const float* bp = bqv + t * 64 + c * 8;
#pragma unroll
                for (int e = 0; e < 8; ++e) hacc += (float)av[e] * bp[e];
            }
        }
        __syncthreads();
    }

    const int rj = (lane >> 4) * 4;
    const int cc = lane & 15;
#pragma unroll
    for (int m = 0; m < 2; ++m) {
#pragma unroll
        for (int n = 0; n < 2; ++n) {
            const int col = n0 + wc * 32 + n * 16 + cc;
            f32x4 vv = acc[m][n];
#pragma unroll
            for (int j = 0; j < 4; ++j) {
                const int row = m0 + wr * 32 + m * 16 + rj + j;
                float val = vv[j];
                if (EPI == 1)
                    val += e0[bz * C_ + row] * e1[col] +
                           e2[row] * (e3[bz * C_ + col] + 2048.0f * e1[col]);
                Cout[(size_t)bz * sC + (size_t)row * C_ + col] = (bf16_t)val;
            }
        }
    }
    if (doH) {
        hacc += __shfl_xor(hacc, 1, 64);
        hacc += __shfl_xor(hacc, 2, 64);
        if ((tid & 3) == 0) hout[bz * C_ + m0 + (tid >> 2)] = hacc;
    }
}

// ---------------------------------------------------------------------------
// Final GEMM: out[c,n] = sum_i HT[c,i]*qT[n,i] + h[b][c] + (float)qc[c,n].
// 1-D swizzled grid (512): the 4 m-blocks sharing a qT n-panel sit at
// stride 8 (same XCD under round-robin) -> panel L2 reuse.
// ---------------------------------------------------------------------------
__global__ __launch_bounds__(256) void gemm_final(
    const bf16_t* __restrict__ A, const bf16_t* __restrict__ Bm,
    float* __restrict__ Cout, const bf16_t* __restrict__ qc,
    const float* __restrict__ hvec)
{
    __shared__ __align__(16) bf16_t As[128 * 64];
    __shared__ __align__(16) bf16_t Bs[128 * 64];

    const int f = blockIdx.x;
    const int xcd = f & 7, sl = f >> 3;
    const int g = xcd + 8 * (sl >> 2);     // g in [0,128): (b, n-panel)
    const int m0 = (sl & 3) * 128;
    const int bz = g >> 4;
    const int n0 = (g & 15) * 128;
    const int K = C_;

    const int tid = threadIdx.x, lane = tid & 63, wave = tid >> 6;
    const int wr = wave >> 1, wc = wave & 1;

    const bf16_t* Ab = A + (size_t)bz * ((size_t)C_ * C_);
    const bf16_t* Bb = Bm + (size_t)bz * ((size_t)N_ * C_);

    f32x4 acc[4][4];
#pragma unroll
    for (int i = 0; i < 4; ++i)
#pragma unroll
        for (int j = 0; j < 4; ++j) acc[i][j] = 0.f;

    const int srow = tid >> 3;
    const int scol = ((tid & 7) ^ (srow & 7)) * 8;
    const int ldso = tid * 16;

    for (int t = 0; t < 8; ++t) {
        const bf16_t* ga = Ab + (size_t)(m0 + srow) * K + t * 64 + scol;
        const bf16_t* gb = Bb + (size_t)(n0 + srow) * K + t * 64 + scol;
#pragma unroll
        for (int p = 0; p < 4; ++p)
            __builtin_amdgcn_global_load_lds(
                (const __attribute__((address_space(1))) void*)(ga + (size_t)p * 32 * K),
                (__attribute__((address_space(3))) void*)((char*)As + ldso + p * 4096),
                16, 0, 0);
#pragma unroll
        for (int p = 0; p < 4; ++p)
            __builtin_amdgcn_global_load_lds(
                (const __attribute__((address_space(1))) void*)(gb + (size_t)p * 32 * K),
                (__attribute__((address_space(3))) void*)((char*)Bs + ldso + p * 4096),
                16, 0, 0);
        __syncthreads();

#pragma unroll
        for (int kk = 0; kk < 64; kk += 32) {
            bf16x8 af[4], bfr[4];
            const int kcol = kk + (lane >> 4) * 8;
            const int kc = kcol >> 3;
#pragma unroll
            for (int m = 0; m < 4; ++m) {
                const int r = wr * 64 + (lane & 15) + m * 16;
                af[m] = *(const bf16x8*)((const char*)As + r * 128 +
                                         ((kc ^ (r & 7)) << 4));
            }
#pragma unroll
            for (int n = 0; n < 4; ++n) {
                const int r = wc * 64 + (lane & 15) + n * 16;
                bfr[n] = *(const bf16x8*)((const char*)Bs + r * 128 +
                                          ((kc ^ (r & 7)) << 4));
            }
#pragma unroll
            for (int m = 0; m < 4; ++m)
#pragma unroll
                for (int n = 0; n < 4; ++n)
                    acc[m][n] = __builtin_amdgcn_mfma_f32_16x16x32_bf16(
                        af[m], bfr[n], acc[m][n], 0, 0, 0);
        }
        __syncthreads();
    }

    const int rj = (lane >> 4) * 4;
    const int cc = lane & 15;
    const size_t ob = (size_t)bz * ((size_t)C_ * N_);
#pragma unroll
    for (int m = 0; m < 4; ++m) {
#pragma unroll
        for (int n = 0; n < 4; ++n) {
            const int col = n0 + wc * 64 + n * 16 + cc;
            f32x4 vv = acc[m][n];
#pragma unroll
            for (int j = 0; j < 4; ++j) {
                const int row = m0 + wr * 64 + m * 16 + rj + j;
                const size_t o = ob + (size_t)row * N_ + col;
                Cout[o] = vv[j] + hvec[bz * C_ + row] + (float)qc[o];
            }
        }
    }
}

// ---------------------------------------------------------------------------
extern "C" void kernel_launch(void* const* d_in, const int* in_sizes, int n_in,
                              void* d_out, int out_size, void* d_ws, size_t ws_size,
                              hipStream_t stream)
{
    (void)in_sizes; (void)n_in; (void)out_size; (void)ws_size;
    const float* q  = (const float*)d_in[0];
    const float* k  = (const float*)d_in[1];
    const float* v  = (const float*)d_in[2];
    const float* wq = (const float*)d_in[3];
    const float* bq = (const float*)d_in[4];
    const float* wk = (const float*)d_in[5];
    const float* bk = (const float*)d_in[6];
    const float* wv = (const float*)d_in[7];
    const float* bv = (const float*)d_in[8];
    float* out = (float*)d_out;

    char* ws = (char*)d_ws;
    const size_t WSZ = (size_t)C_ * C_ * 2;            // 512 KB
    const size_t TSZ = (size_t)B_ * N_ * C_ * 2;       // 16.78 MB
    const size_t SCZ = (size_t)B_ * C_ * C_ * 2;       // 4.19 MB
    const size_t VSZ = (size_t)B_ * C_ * 4;            // 16 KB
    size_t off = 0;
    bf16_t* Wkb  = (bf16_t*)(ws + off); off += WSZ;
    bf16_t* Wvb  = (bf16_t*)(ws + off); off += WSZ;
    bf16_t* WqTb = (bf16_t*)(ws + off); off += WSZ;
    bf16_t* qT   = (bf16_t*)(ws + off); off += TSZ;
    bf16_t* qc   = (bf16_t*)(ws + off); off += TSZ;
    bf16_t* Dp   = (bf16_t*)(ws + off); off += TSZ;
    bf16_t* D    = (bf16_t*)(ws + off); off += SCZ;
    bf16_t* P1   = (bf16_t*)(ws + off); off += SCZ;
    bf16_t* St   = (bf16_t*)(ws + off); off += SCZ;
    bf16_t* HT   = (bf16_t*)(ws + off); off += SCZ;
    float*  sk4  = (float*)(ws + off);  off += 4 * VSZ;
    float*  sv4  = (float*)(ws + off);  off += 4 * VSZ;
    float*  uu   = (float*)(ws + off);  off += VSZ;
    float*  wwv  = (float*)(ws + off);  off += VSZ;
    float*  hb   = (float*)(ws + off);  off += VSZ;

    const dim3 blk(256);
    const size_t sCC = (size_t)C_ * C_;

    // 1. weights (Wk,Wv cast + Wq transpose) in one dispatch
    weights_kernel<<<dim3(192), blk, 0, stream>>>(wq, wk, wv, WqTb, Wkb, Wvb);

    // 2. q -> qT (bf16 [B,N,C]) + qc (bf16 [B,C,N])
    prep_q_kernel<<<dim3(N_ / 64, C_ / 64, B_), blk, 0, stream>>>(q, qT, qc);

    // 3. D partials from fp32 k,v directly (split-K 4, XCD-swizzled) + sk4/sv4
    gemm_dkv<<<dim3(512), blk, 0, stream>>>(k, v, Dp, sk4, sv4);

    // 4. reduce Dp -> D;  u = Wv.sv, w = Wk.sk  (one dispatch)
    reduce_mv_kernel<<<dim3(1040), blk, 0, stream>>>(
        Dp, D, Wvb, Wkb, sk4, sv4, uu, wwv);

    // 5. P1[c2,i] = sum_j Wv[c2,j] D[i,j]
    gemm64_nt<0><<<dim3(C_ / 64, C_ / 64, B_), blk, 0, stream>>>(
        Wvb, D, P1, 0, sCC, sCC, nullptr, nullptr, nullptr, nullptr, nullptr, nullptr);

    // 6. St = P1.Wk^T + u bk^T + bv (w + N bk)^T
    gemm64_nt<1><<<dim3(C_ / 64, C_ / 64, B_), blk, 0, stream>>>(
        P1, Wkb, St, sCC, 0, sCC, uu, bk, bv, wwv, nullptr, nullptr);

    // 7. HT = St.Wq  (+ h = St.bq computed by x==0 blocks)
    gemm64_nt<2><<<dim3(C_ / 64, C_ / 64, B_), blk, 0, stream>>>(
        St, WqTb, HT, sCC, 0, sCC, nullptr, nullptr, nullptr, nullptr, bq, hb);

    // 8. out = HT.qT^T + h + qc   (fp32, final layout, XCD-swizzled)
    gemm_final<<<dim3(512), blk, 0, stream>>>(HT, qT, out, qc, hb);
}